// Round 4
// baseline (3531.164 us; speedup 1.0000x reference)
//
#include <hip/hip_runtime.h>
#include <stdint.h>

typedef __attribute__((ext_vector_type(8))) short short8;
typedef __attribute__((ext_vector_type(4))) float floatx4;

static constexpr int kB = 64, kS = 512, kN = 2048;
static constexpr int RING = 4;   // e-slab ring; >=3 needed (max producer/consumer skew)

// ---- workspace layout (bytes) ----
// flg: [kS+1][4 bg][64 cg][16 r] float partial-rowsums, doubling as arrival flags.
// Strictly positive when written (sum of exp) -> "!= 0" is the arrival signal.
// Zeroed by captured memset each launch. Slot kS = h0-publication round.
static constexpr size_t FLG_OFF    = 0;
static constexpr size_t FLG_BYTES  = (size_t)(kS + 1) * 4 * 64 * 16 * 4;  // 8,404,992
static constexpr size_t EBUF_OFF   = (FLG_BYTES + 4095) & ~(size_t)4095; // 4 KiB aligned
static constexpr size_t SLAB_ELEMS = (size_t)kB * kN;                    // ushorts per slab

__device__ __forceinline__ unsigned short f2bf(float x) {
    unsigned u = __builtin_bit_cast(unsigned, x);
    u = (u + 0x7fffu + ((u >> 16) & 1u)) >> 16;   // RNE fp32 -> bf16
    return (unsigned short)u;
}

struct ULL2 { unsigned long long lo, hi; };

// ================== 256 blocks x 256 thr, 139 KiB LDS, 1 block/CU ==================
// Block (bg,cg): batch rows [bg*16,+16), cols [cg*32,+32). Domain bg = 64 blocks on
// XCD pair {2bg, 2bg+1} (blockIdx%8 swizzle). No central barrier counter: per-step
// distributed flags (the rowsum partials). Protocol per step:
//   e-stores (agent sc) -> __syncthreads (vmcnt0 drain: e at coherence point)
//   -> flag store (agent sc) -> consumers poll flags with cache-bypassing loads.
// Any flag from block cg nonzero => cg's WHOLE e-tile visible (stored pre-drain).
__global__ __launch_bounds__(256) void pcn(
    const float* __restrict__ vel, const float* __restrict__ h0,
    const float* __restrict__ Wlin, const float* __restrict__ blin,
    const float* __restrict__ Wrec, float* __restrict__ out,
    float* flg, unsigned short* ebuf)
{
    extern __shared__ char smem[];
    short8* Wlds = (short8*)smem;            // [64 kt][2 ct][64 lanes] = 128 KiB
    float*  red  = (float*)(smem + 131072);  // [4 waves][512 cells]   = 8 KiB

    const int tid  = threadIdx.x;
    const int lane = tid & 63;
    const int w    = tid >> 6;
    const int bg   = (blockIdx.x & 7) >> 1;                       // 0..3
    const int cg   = ((blockIdx.x >> 3) << 1) | (blockIdx.x & 1); // 0..63
    const int b0   = bg * 16;
    const int c0   = cg * 32;
    const int koff = (lane >> 4) << 3;  // quad*8: k-offset of this lane's A/B fragment

    // ---- one-time: stage W_rec[k, c0..c0+31] into LDS, B-fragment order ----
    for (int kt = w * 16; kt < w * 16 + 16; ++kt) {
        for (int ct = 0; ct < 2; ++ct) {
            const int colg = c0 + ct * 16 + (lane & 15);
            const int kb   = kt * 32 + koff;
            short8 v;
            #pragma unroll
            for (int j = 0; j < 8; ++j)
                v[j] = (short)f2bf(Wrec[(size_t)(kb + j) * kN + colg]);
            Wlds[(kt * 2 + ct) * 64 + lane] = v;
        }
    }

    const int r   = tid >> 4;        // 0..15: row in tile
    const int c16 = tid & 15;
    const int cc  = c16 * 2;         // even col in tile (2 adjacent cols/thread)

    // h0 -> slab 0 (agent-scope publication)
    {
        const float a0 = h0[(size_t)(b0 + r) * kN + c0 + cc];
        const float a1 = h0[(size_t)(b0 + r) * kN + c0 + cc + 1];
        const unsigned pk = (unsigned)f2bf(a0) | ((unsigned)f2bf(a1) << 16);
        __hip_atomic_store((unsigned*)(ebuf + (size_t)(b0 + r) * kN + c0 + cc), pk,
                           __ATOMIC_RELAXED, __HIP_MEMORY_SCOPE_AGENT);
    }

    const float wl00 = Wlin[(c0 + cc) * 2 + 0],     wl01 = Wlin[(c0 + cc) * 2 + 1];
    const float wl10 = Wlin[(c0 + cc + 1) * 2 + 0], wl11 = Wlin[(c0 + cc + 1) * 2 + 1];
    const float bl0  = blin[c0 + cc], bl1 = blin[c0 + cc + 1];

    // publish h0 arrival (slot kS) and wait for whole domain
    __syncthreads();   // drains h0 slab stores
    if (c16 == 0)
        __hip_atomic_store(flg + (((size_t)kS * 4 + bg) * 64 + cg) * 16 + r, 1.0f,
                           __ATOMIC_RELAXED, __HIP_MEMORY_SCOPE_AGENT);
    {
        const float* fpb = flg + ((size_t)kS * 4 + bg) * 64 * 16 + r;
        bool rdy = false;
        do {
            const float p0 = __hip_atomic_load(fpb + (c16 * 4 + 0) * 16, __ATOMIC_RELAXED, __HIP_MEMORY_SCOPE_AGENT);
            const float p1 = __hip_atomic_load(fpb + (c16 * 4 + 1) * 16, __ATOMIC_RELAXED, __HIP_MEMORY_SCOPE_AGENT);
            const float p2 = __hip_atomic_load(fpb + (c16 * 4 + 2) * 16, __ATOMIC_RELAXED, __HIP_MEMORY_SCOPE_AGENT);
            const float p3 = __hip_atomic_load(fpb + (c16 * 4 + 3) * 16, __ATOMIC_RELAXED, __HIP_MEMORY_SCOPE_AGENT);
            rdy = (p0 != 0.f) & (p1 != 0.f) & (p2 != 0.f) & (p3 != 0.f);
        } while (!__all((int)rdy));
    }

    float s_inv = 1.0f;              // h0 enters unnormalized (reference semantics)
    const int arow = b0 + (lane & 15);

    for (int t = 0; t < kS; ++t) {
        // prefetch vel early (independent of flags)
        const float2 vv = *(const float2*)(vel + ((size_t)(b0 + r) * kS + t) * 2);

        // ---- phase 1: issue ALL A-fragment loads (cache-bypassing; ring slab
        // addresses recycle, a cached line from step t-RING would be stale) ----
        const unsigned short* ebR = ebuf + (size_t)(t % RING) * SLAB_ELEMS;
        ULL2 afrag[16];
        #pragma unroll
        for (int kt = 0; kt < 16; ++kt) {
            const int ktg = w * 16 + kt;
            const unsigned long long* ap =
                (const unsigned long long*)(ebR + (size_t)arow * kN + ktg * 32 + koff);
            afrag[kt].lo = __hip_atomic_load(ap,     __ATOMIC_RELAXED, __HIP_MEMORY_SCOPE_AGENT);
            afrag[kt].hi = __hip_atomic_load(ap + 1, __ATOMIC_RELAXED, __HIP_MEMORY_SCOPE_AGENT);
        }
        // ---- phase 2: MFMA over this wave's K-slice ----
        floatx4 acc0 = {0.f,0.f,0.f,0.f}, acc1 = {0.f,0.f,0.f,0.f};
        #pragma unroll
        for (int kt = 0; kt < 16; ++kt) {
            const int ktg = w * 16 + kt;
            const short8 a   = __builtin_bit_cast(short8, afrag[kt]);
            const short8 bq0 = Wlds[(ktg * 2 + 0) * 64 + lane];
            const short8 bq1 = Wlds[(ktg * 2 + 1) * 64 + lane];
            acc0 = __builtin_amdgcn_mfma_f32_16x16x32_bf16(a, bq0, acc0, 0, 0, 0);
            acc1 = __builtin_amdgcn_mfma_f32_16x16x32_bf16(a, bq1, acc1, 0, 0, 0);
        }
        // cross-wave K reduce via LDS (C/D layout: col=lane&15, row=quad*4+i)
        {
            const int ccol = lane & 15, crow = (lane >> 4) * 4;
            #pragma unroll
            for (int i = 0; i < 4; ++i) {
                red[w * 512 + (crow + i) * 32 + ccol]      = acc0[i];
                red[w * 512 + (crow + i) * 32 + 16 + ccol] = acc1[i];
            }
        }
        __syncthreads();
        float g0 = 0.f, g1 = 0.f;
        {
            const int cell = tid * 2;
            #pragma unroll
            for (int ww = 0; ww < 4; ++ww) {
                g0 += red[ww * 512 + cell];
                g1 += red[ww * 512 + cell + 1];
            }
        }

        // ---- epilogue: z = base_logits + g/s_prev ; e = exp(z) ----
        const float z0 = fmaf(g0, s_inv, fmaf(vv.x, wl00, fmaf(vv.y, wl01, bl0)));
        const float z1 = fmaf(g1, s_inv, fmaf(vv.x, wl10, fmaf(vv.y, wl11, bl1)));
        const float e0 = __expf(z0), e1 = __expf(z1);

        // 32-col row partial (16 threads/row, intra-wave butterfly -> all lanes)
        float es = e0 + e1;
        es += __shfl_xor(es, 8, 16);
        es += __shfl_xor(es, 4, 16);
        es += __shfl_xor(es, 2, 16);
        es += __shfl_xor(es, 1, 16);

        // publish unnormalized e_t (agent-scope 4B store) into ring slab t+1
        {
            const unsigned pk = (unsigned)f2bf(e0) | ((unsigned)f2bf(e1) << 16);
            __hip_atomic_store(
                (unsigned*)(ebuf + (size_t)((t + 1) % RING) * SLAB_ELEMS
                            + (size_t)(b0 + r) * kN + c0 + cc),
                pk, __ATOMIC_RELAXED, __HIP_MEMORY_SCOPE_AGENT);
        }

        __syncthreads();   // vmcnt(0) drain: ALL e stores at coherence point

        // arrival flag = rowsum partial (strictly positive)
        if (c16 == 0)
            __hip_atomic_store(flg + (((size_t)t * 4 + bg) * 64 + cg) * 16 + r, es,
                               __ATOMIC_RELAXED, __HIP_MEMORY_SCOPE_AGENT);

        // poll domain flags for step t (doubles as rowsum reduction)
        float p0, p1, p2, p3;
        {
            const float* fpb = flg + ((size_t)t * 4 + bg) * 64 * 16 + r;
            bool rdy = false;
            do {
                p0 = __hip_atomic_load(fpb + (c16 * 4 + 0) * 16, __ATOMIC_RELAXED, __HIP_MEMORY_SCOPE_AGENT);
                p1 = __hip_atomic_load(fpb + (c16 * 4 + 1) * 16, __ATOMIC_RELAXED, __HIP_MEMORY_SCOPE_AGENT);
                p2 = __hip_atomic_load(fpb + (c16 * 4 + 2) * 16, __ATOMIC_RELAXED, __HIP_MEMORY_SCOPE_AGENT);
                p3 = __hip_atomic_load(fpb + (c16 * 4 + 3) * 16, __ATOMIC_RELAXED, __HIP_MEMORY_SCOPE_AGENT);
                rdy = (p0 != 0.f) & (p1 != 0.f) & (p2 != 0.f) & (p3 != 0.f);
            } while (!__all((int)rdy));
        }
        float s = (p0 + p1) + (p2 + p3);
        s += __shfl_xor(s, 8, 16);
        s += __shfl_xor(s, 4, 16);
        s += __shfl_xor(s, 2, 16);
        s += __shfl_xor(s, 1, 16);
        s_inv = 1.0f / s;

        // normalized output for step t (plain stores; drained by next step's sync)
        {
            float2 o; o.x = e0 * s_inv; o.y = e1 * s_inv;
            *(float2*)(out + ((size_t)(b0 + r) * kS + t) * kN + c0 + cc) = o;
        }
    }
}

extern "C" void kernel_launch(void* const* d_in, const int* in_sizes, int n_in,
                              void* d_out, int out_size, void* d_ws, size_t ws_size,
                              hipStream_t stream)
{
    (void)in_sizes; (void)n_in; (void)out_size; (void)ws_size;
    const float* vel  = (const float*)d_in[0];
    const float* h0   = (const float*)d_in[1];
    const float* Wlin = (const float*)d_in[2];
    const float* blin = (const float*)d_in[3];
    const float* Wrec = (const float*)d_in[4];
    float* out = (float*)d_out;

    char* ws = (char*)d_ws;
    float* flg           = (float*)(ws + FLG_OFF);
    unsigned short* ebuf = (unsigned short*)(ws + EBUF_OFF);

    // flags must start at 0 (ws is poisoned 0xAA each launch); slabs need no init
    (void)hipMemsetAsync(ws + FLG_OFF, 0, FLG_BYTES, stream);

    const unsigned smem = 131072 + 8192;   // 139264 B dynamic LDS -> 1 block/CU
    (void)hipFuncSetAttribute((const void*)pcn,
        hipFuncAttributeMaxDynamicSharedMemorySize, (int)smem);

    void* args[] = { (void*)&vel, (void*)&h0, (void*)&Wlin, (void*)&blin,
                     (void*)&Wrec, (void*)&out, (void*)&flg, (void*)&ebuf };
    hipError_t err = hipLaunchCooperativeKernel((const void*)pcn,
        dim3(256), dim3(256), args, smem, stream);
    if (err != hipSuccess) {
        (void)hipGetLastError();
        // plain launch: 256 blocks @ 1 block/CU are co-resident by capacity
        hipLaunchKernelGGL(pcn, dim3(256), dim3(256), smem, stream,
                           vel, h0, Wlin, blin, Wrec, out, flg, ebuf);
    }
}

// Round 5
// 2318.280 us; speedup vs baseline: 1.5232x; 1.5232x over previous
//
#include <hip/hip_runtime.h>
#include <stdint.h>

typedef __attribute__((ext_vector_type(8))) short short8;
typedef __attribute__((ext_vector_type(4))) float floatx4;

static constexpr int kB = 64, kS = 512, kN = 2048;

// ---- workspace layout (bytes) ----
// part: [kS+1][4 bg][16 r][64 cg] float — per-producer partial rowsums doubling as
// write-once arrival flags (strictly positive when written; "!=0" = arrived).
// Slot kS = h0-publication round. Zeroed by captured memset each launch.
// slabs: [kS][kB][kN] ushort bf16 — slab 0 = h0, slab t+1 = e_t (write-once per
// launch -> consumers may use PLAIN CACHED loads: fresh addresses can't be stale,
// and 31/32 blocks per XCD hit their L2 copy instead of IC).
static constexpr size_t PART_OFF   = 0;
static constexpr size_t PART_BYTES = (size_t)(kS + 1) * 4 * 16 * 64 * 4;  // 8,404,992
static constexpr size_t EBUF_OFF   = PART_BYTES;                          // 4096-aligned
static constexpr size_t SLAB_ELEMS = (size_t)kB * kN;                     // 131072
// total = 8,404,992 + 512*262,144 = 142,622,720 B  (< round-3-proven ws bound)

__device__ __forceinline__ unsigned short f2bf(float x) {
    unsigned u = __builtin_bit_cast(unsigned, x);
    u = (u + 0x7fffu + ((u >> 16) & 1u)) >> 16;   // RNE fp32 -> bf16
    return (unsigned short)u;
}

// ================== 256 blocks x 256 thr, 139 KiB LDS, 1 block/CU ==================
// Block (bg,cg): batch rows [bg*16,+16), cols [cg*32,+32). Domain bg = 64 blocks on
// XCD pair {2bg,2bg+1} (blockIdx%8 swizzle). No atomics at all. Per step:
//   e-stores (agent-scope write-through) -> __syncthreads (vmcnt0: e at IC)
//   -> partial-flag store (agent) -> all consumers poll the 64 partials for their
//   row (cache-bypassing loads) and reduce them = the rowsum. Flag from cg nonzero
//   => cg's whole e-tile is at the coherence point (stored pre-drain).
__global__ __launch_bounds__(256) void pcn(
    const float* __restrict__ vel, const float* __restrict__ h0,
    const float* __restrict__ Wlin, const float* __restrict__ blin,
    const float* __restrict__ Wrec, float* __restrict__ out,
    float* part, unsigned short* ebuf)
{
    extern __shared__ char smem[];
    short8* Wlds = (short8*)smem;            // [64 kt][2 ct][64 lanes] = 128 KiB
    float*  red  = (float*)(smem + 131072);  // [4 waves][512 cells]   = 8 KiB

    const int tid  = threadIdx.x;
    const int lane = tid & 63;
    const int w    = tid >> 6;
    const int bg   = (blockIdx.x & 7) >> 1;                       // 0..3
    const int cg   = ((blockIdx.x >> 3) << 1) | (blockIdx.x & 1); // 0..63
    const int b0   = bg * 16;
    const int c0   = cg * 32;
    const int koff = (lane >> 4) << 3;  // quad*8: k-offset of this lane's A/B fragment

    // ---- one-time: stage W_rec[k, c0..c0+31] into LDS, B-fragment order ----
    for (int kt = w * 16; kt < w * 16 + 16; ++kt) {
        for (int ct = 0; ct < 2; ++ct) {
            const int colg = c0 + ct * 16 + (lane & 15);
            const int kb   = kt * 32 + koff;
            short8 v;
            #pragma unroll
            for (int j = 0; j < 8; ++j)
                v[j] = (short)f2bf(Wrec[(size_t)(kb + j) * kN + colg]);
            Wlds[(kt * 2 + ct) * 64 + lane] = v;
        }
    }

    const int r   = tid >> 4;        // 0..15: row in tile
    const int c16 = tid & 15;
    const int cc  = c16 * 2;         // even col in tile (2 adjacent cols/thread)

    // h0 -> slab 0 (agent-scope write-through publication)
    {
        const float a0 = h0[(size_t)(b0 + r) * kN + c0 + cc];
        const float a1 = h0[(size_t)(b0 + r) * kN + c0 + cc + 1];
        const unsigned pk = (unsigned)f2bf(a0) | ((unsigned)f2bf(a1) << 16);
        __hip_atomic_store((unsigned*)(ebuf + (size_t)(b0 + r) * kN + c0 + cc), pk,
                           __ATOMIC_RELAXED, __HIP_MEMORY_SCOPE_AGENT);
    }

    const float wl00 = Wlin[(c0 + cc) * 2 + 0],     wl01 = Wlin[(c0 + cc) * 2 + 1];
    const float wl10 = Wlin[(c0 + cc + 1) * 2 + 0], wl11 = Wlin[(c0 + cc + 1) * 2 + 1];
    const float bl0  = blin[c0 + cc], bl1 = blin[c0 + cc + 1];

    // publish h0 arrival (slot kS) and wait for whole domain
    __syncthreads();   // drains h0 slab stores (vmcnt0 -> acks from coherence point)
    if (c16 == 0)
        __hip_atomic_store(part + (((size_t)kS * 4 + bg) * 16 + r) * 64 + cg, 1.0f,
                           __ATOMIC_RELAXED, __HIP_MEMORY_SCOPE_AGENT);
    {
        const float* fpb = part + (((size_t)kS * 4 + bg) * 16 + r) * 64 + c16 * 4;
        bool rdy = false;
        int spin = 0;
        do {
            const float p0 = __hip_atomic_load(fpb + 0, __ATOMIC_RELAXED, __HIP_MEMORY_SCOPE_AGENT);
            const float p1 = __hip_atomic_load(fpb + 1, __ATOMIC_RELAXED, __HIP_MEMORY_SCOPE_AGENT);
            const float p2 = __hip_atomic_load(fpb + 2, __ATOMIC_RELAXED, __HIP_MEMORY_SCOPE_AGENT);
            const float p3 = __hip_atomic_load(fpb + 3, __ATOMIC_RELAXED, __HIP_MEMORY_SCOPE_AGENT);
            rdy = (p0 != 0.f) & (p1 != 0.f) & (p2 != 0.f) & (p3 != 0.f);
            if (++spin > 8) __builtin_amdgcn_s_sleep(1);
        } while (!__all((int)rdy));
    }

    float s_inv = 1.0f;              // h0 enters unnormalized (reference semantics)
    const int arow = b0 + (lane & 15);

    for (int t = 0; t < kS; ++t) {
        // vel prefetch (independent of flags)
        const float2 vv = *(const float2*)(vel + ((size_t)(b0 + r) * kS + t) * 2);

        // ---- phase 1: all A-fragment loads, PLAIN CACHED (write-once slab t) ----
        const unsigned short* ebR = ebuf + (size_t)t * SLAB_ELEMS;
        short8 afrag[16];
        #pragma unroll
        for (int kt = 0; kt < 16; ++kt)
            afrag[kt] = *(const short8*)(ebR + (size_t)arow * kN + (w * 16 + kt) * 32 + koff);

        // ---- phase 2: MFMA over this wave's K-slice ----
        floatx4 acc0 = {0.f,0.f,0.f,0.f}, acc1 = {0.f,0.f,0.f,0.f};
        #pragma unroll
        for (int kt = 0; kt < 16; ++kt) {
            const int ktg = w * 16 + kt;
            const short8 bq0 = Wlds[(ktg * 2 + 0) * 64 + lane];
            const short8 bq1 = Wlds[(ktg * 2 + 1) * 64 + lane];
            acc0 = __builtin_amdgcn_mfma_f32_16x16x32_bf16(afrag[kt], bq0, acc0, 0, 0, 0);
            acc1 = __builtin_amdgcn_mfma_f32_16x16x32_bf16(afrag[kt], bq1, acc1, 0, 0, 0);
        }
        // cross-wave K reduce via LDS (C/D layout: col=lane&15, row=quad*4+i)
        {
            const int ccol = lane & 15, crow = (lane >> 4) * 4;
            #pragma unroll
            for (int i = 0; i < 4; ++i) {
                red[w * 512 + (crow + i) * 32 + ccol]      = acc0[i];
                red[w * 512 + (crow + i) * 32 + 16 + ccol] = acc1[i];
            }
        }
        __syncthreads();
        float g0 = 0.f, g1 = 0.f;
        {
            const int cell = tid * 2;
            #pragma unroll
            for (int ww = 0; ww < 4; ++ww) {
                g0 += red[ww * 512 + cell];
                g1 += red[ww * 512 + cell + 1];
            }
        }

        // ---- epilogue: z = base_logits + g/s_prev ; e = exp(z) ----
        const float z0 = fmaf(g0, s_inv, fmaf(vv.x, wl00, fmaf(vv.y, wl01, bl0)));
        const float z1 = fmaf(g1, s_inv, fmaf(vv.x, wl10, fmaf(vv.y, wl11, bl1)));
        const float e0 = __expf(z0), e1 = __expf(z1);

        // 32-col row partial (16 threads/row, intra-wave butterfly -> all lanes)
        float es = e0 + e1;
        es += __shfl_xor(es, 8, 16);
        es += __shfl_xor(es, 4, 16);
        es += __shfl_xor(es, 2, 16);
        es += __shfl_xor(es, 1, 16);

        // publish unnormalized e_t into write-once slab t+1 (dead at t=511)
        if (t < kS - 1) {
            const unsigned pk = (unsigned)f2bf(e0) | ((unsigned)f2bf(e1) << 16);
            __hip_atomic_store(
                (unsigned*)(ebuf + (size_t)(t + 1) * SLAB_ELEMS + (size_t)(b0 + r) * kN + c0 + cc),
                pk, __ATOMIC_RELAXED, __HIP_MEMORY_SCOPE_AGENT);
        }

        __syncthreads();   // vmcnt(0): ALL e stores acked at coherence point

        // arrival flag = rowsum partial (strictly positive), r-major layout
        if (c16 == 0)
            __hip_atomic_store(part + (((size_t)t * 4 + bg) * 16 + r) * 64 + cg, es,
                               __ATOMIC_RELAXED, __HIP_MEMORY_SCOPE_AGENT);

        // poll domain flags for step t (doubles as rowsum reduction);
        // thread (r,c16) polls 16B span [r][c16*4..+4] — one line per thread
        float p0, p1, p2, p3;
        {
            const float* fpb = part + (((size_t)t * 4 + bg) * 16 + r) * 64 + c16 * 4;
            bool rdy = false;
            int spin = 0;
            do {
                p0 = __hip_atomic_load(fpb + 0, __ATOMIC_RELAXED, __HIP_MEMORY_SCOPE_AGENT);
                p1 = __hip_atomic_load(fpb + 1, __ATOMIC_RELAXED, __HIP_MEMORY_SCOPE_AGENT);
                p2 = __hip_atomic_load(fpb + 2, __ATOMIC_RELAXED, __HIP_MEMORY_SCOPE_AGENT);
                p3 = __hip_atomic_load(fpb + 3, __ATOMIC_RELAXED, __HIP_MEMORY_SCOPE_AGENT);
                rdy = (p0 != 0.f) & (p1 != 0.f) & (p2 != 0.f) & (p3 != 0.f);
                if (++spin > 8) __builtin_amdgcn_s_sleep(1);
            } while (!__all((int)rdy));
        }
        float s = (p0 + p1) + (p2 + p3);
        s += __shfl_xor(s, 8, 16);
        s += __shfl_xor(s, 4, 16);
        s += __shfl_xor(s, 2, 16);
        s += __shfl_xor(s, 1, 16);
        s_inv = 1.0f / s;

        // normalized output for step t (plain cached stores)
        {
            float2 o; o.x = e0 * s_inv; o.y = e1 * s_inv;
            *(float2*)(out + ((size_t)(b0 + r) * kS + t) * kN + c0 + cc) = o;
        }
    }
}

extern "C" void kernel_launch(void* const* d_in, const int* in_sizes, int n_in,
                              void* d_out, int out_size, void* d_ws, size_t ws_size,
                              hipStream_t stream)
{
    (void)in_sizes; (void)n_in; (void)out_size; (void)ws_size;
    const float* vel  = (const float*)d_in[0];
    const float* h0   = (const float*)d_in[1];
    const float* Wlin = (const float*)d_in[2];
    const float* blin = (const float*)d_in[3];
    const float* Wrec = (const float*)d_in[4];
    float* out = (float*)d_out;

    char* ws = (char*)d_ws;
    float* part          = (float*)(ws + PART_OFF);
    unsigned short* ebuf = (unsigned short*)(ws + EBUF_OFF);

    // flags must start at 0 (ws is poisoned 0xAA each launch); slabs need no init
    (void)hipMemsetAsync(ws + PART_OFF, 0, PART_BYTES, stream);

    const unsigned smem = 131072 + 8192;   // 139264 B dynamic LDS -> 1 block/CU
    (void)hipFuncSetAttribute((const void*)pcn,
        hipFuncAttributeMaxDynamicSharedMemorySize, (int)smem);

    void* args[] = { (void*)&vel, (void*)&h0, (void*)&Wlin, (void*)&blin,
                     (void*)&Wrec, (void*)&out, (void*)&part, (void*)&ebuf };
    hipError_t err = hipLaunchCooperativeKernel((const void*)pcn,
        dim3(256), dim3(256), args, smem, stream);
    if (err != hipSuccess) {
        (void)hipGetLastError();
        // plain launch: 256 blocks @ 1 block/CU are co-resident by capacity
        hipLaunchKernelGGL(pcn, dim3(256), dim3(256), smem, stream,
                           vel, h0, Wlin, blin, Wrec, out, part, ebuf);
    }
}